// Round 2
// baseline (883.403 us; speedup 1.0000x reference)
//
#include <hip/hip_runtime.h>
#include <math.h>

// ---------------- constants ----------------
#define B 2
#define DIM 512
#define N1 1024
#define SIDE1 32
#define N2 2048
#define SIDE2 46
#define NSAMPLE 64
#define SLOPE 0.2f

// workspace layout (float offsets)
#define FEAT_OFF   0                       // (B,1024,N2)  h3 rows 0..511, local rows 512..1023
#define FEAT_BSTR  (1024*N2)
#define BUFA_OFF   (B*1024*N2)             // (B,512,N2)
#define BUFB_OFF   (BUFA_OFF + B*512*N2)   // (B,512,N2)
#define C1_OFF     (BUFB_OFF + B*512*N2)   // (B,512)
#define GLOB_OFF   (C1_OFF + B*512)        // (B,512)
#define GBIAS_OFF  (GLOB_OFF + B*512)      // (B,512)

// ---------------- per-(b,o) GEMV: c1 = W1a[:, :512] @ z + b1a ----------------
__global__ void k_c1(const float* __restrict__ z,
                     const float* __restrict__ W1a,
                     const float* __restrict__ b1a,
                     float* __restrict__ c1) {
    int gid = blockIdx.x * 4 + (threadIdx.x >> 6);   // 0..1023
    int lane = threadIdx.x & 63;
    int b = gid >> 9, o = gid & 511;
    float acc = 0.f;
    const float* wr = W1a + (long)o * 514;
    const float* zb = z + b * 512;
    for (int k = lane; k < 512; k += 64) acc += wr[k] * zb[k];
    #pragma unroll
    for (int off = 32; off > 0; off >>= 1) acc += __shfl_down(acc, off, 64);
    if (lane == 0) c1[gid] = acc + b1a[o];
}

// ---------------- gbias = W2a[:,1024:1536] @ glob + b2a ----------------
__global__ void k_gbias(const float* __restrict__ W2a,
                        const float* __restrict__ b2a,
                        const float* __restrict__ glob,
                        float* __restrict__ gbias) {
    int gid = blockIdx.x * 4 + (threadIdx.x >> 6);
    int lane = threadIdx.x & 63;
    int b = gid >> 9, o = gid & 511;
    float acc = 0.f;
    const float* wr = W2a + (long)o * 1536 + 1024;
    const float* gb = glob + b * 512;
    for (int k = lane; k < 512; k += 64) acc += wr[k] * gb[k];
    #pragma unroll
    for (int off = 32; off > 0; off >>= 1) acc += __shfl_down(acc, off, 64);
    if (lane == 0) gbias[gid] = acc + b2a[o];
}

// ---------------- stage1 layer a (pointwise rank-2 update) ----------------
__global__ void k_layer_a(const float* __restrict__ W1a,
                          const float* __restrict__ c1,
                          float* __restrict__ out, int N, int side) {
    int idx = blockIdx.x * 256 + threadIdx.x;
    int n = idx % N;
    int o = (idx / N) & 511;
    int b = idx / (N * 512);
    int row = n / side, col = n % side;
    double inv = 1.0 / (double)(side - 1);
    float lx = (row == side - 1) ? 1.0f : (float)(row * inv);
    float ly = (col == side - 1) ? 1.0f : (float)(col * inv);
    float w512 = W1a[(long)o * 514 + 512];
    float w513 = W1a[(long)o * 514 + 513];
    float h = c1[b * 512 + o] + w512 * lx + w513 * ly;
    out[(long)b * 512 * N + (long)o * N + n] = (h > 0.f) ? h : SLOPE * h;
}

// ---------------- tiled fp32 GEMM + leaky: Y(B,512,N) = act(W(512xK)@X(B,K,N)+bias) ----
__global__ __launch_bounds__(256) void k_gemm_leaky(
    const float* __restrict__ W, int wstride,
    const float* __restrict__ X, long xb,
    const float* __restrict__ bias, int biasb,
    float* __restrict__ Y, long yb,
    int K, int N) {
    int b = blockIdx.z;
    int o0 = blockIdx.y * 64, n0 = blockIdx.x * 64;
    const float* Xb = X + (long)b * xb;
    float* Yb = Y + (long)b * yb;
    __shared__ float wsm[16][64];
    __shared__ float xsm[16][64];
    int tid = threadIdx.x;
    int tx = tid & 15, ty = tid >> 4;
    float acc[4][4] = {};
    for (int k0 = 0; k0 < K; k0 += 16) {
        #pragma unroll
        for (int l = tid; l < 64 * 16; l += 256) {
            int kk = l & 15, oo = l >> 4;
            wsm[kk][oo] = W[(long)(o0 + oo) * wstride + k0 + kk];
        }
        #pragma unroll
        for (int l = tid; l < 16 * 64; l += 256) {
            int nn = l & 63, kk = l >> 6;
            xsm[kk][nn] = Xb[(long)(k0 + kk) * N + n0 + nn];
        }
        __syncthreads();
        #pragma unroll
        for (int k = 0; k < 16; ++k) {
            float wv[4], xv[4];
            #pragma unroll
            for (int i = 0; i < 4; ++i) wv[i] = wsm[k][ty * 4 + i];
            #pragma unroll
            for (int j = 0; j < 4; ++j) xv[j] = xsm[k][tx * 4 + j];
            #pragma unroll
            for (int i = 0; i < 4; ++i)
                #pragma unroll
                for (int j = 0; j < 4; ++j) acc[i][j] += wv[i] * xv[j];
        }
        __syncthreads();
    }
    #pragma unroll
    for (int i = 0; i < 4; ++i) {
        int o = o0 + ty * 4 + i;
        float bv = bias[biasb * b + o];
        #pragma unroll
        for (int j = 0; j < 4; ++j) {
            float v = acc[i][j] + bv;
            v = (v > 0.f) ? v : SLOPE * v;
            Yb[(long)o * N + n0 + tx * 4 + j] = v;
        }
    }
}

// ---------------- 3-channel projection head + sigmoid - 0.5 ----------------
__global__ void k_proj_head(const float* __restrict__ Wx,
                            const float* __restrict__ bx,
                            const float* __restrict__ H, long hb, int N,
                            float* __restrict__ out) {
    __shared__ float w[1536];
    __shared__ float bb[3];
    int tid = threadIdx.x;
    for (int l = tid; l < 1536; l += 256) w[l] = Wx[l];
    if (tid < 3) bb[tid] = bx[tid];
    __syncthreads();
    int b = blockIdx.y;
    int n = blockIdx.x * 256 + tid;
    const float* Hb = H + (long)b * hb;
    float a0 = 0.f, a1 = 0.f, a2 = 0.f;
    for (int k = 0; k < 512; ++k) {
        float v = Hb[(long)k * N + n];
        a0 += w[k] * v; a1 += w[512 + k] * v; a2 += w[1024 + k] * v;
    }
    float p0 = 1.f / (1.f + expf(-(a0 + bb[0]))) - 0.5f;
    float p1 = 1.f / (1.f + expf(-(a1 + bb[1]))) - 0.5f;
    float p2 = 1.f / (1.f + expf(-(a2 + bb[2]))) - 0.5f;
    long base = ((long)b * N + n) * 3;
    out[base + 0] = p0;
    out[base + 1] = p1;
    out[base + 2] = p2;
}

// ---------------- final head: fine + 0.1*(sigmoid-0.5) ----------------
__global__ void k_final_head(const float* __restrict__ Wx,
                             const float* __restrict__ bx,
                             const float* __restrict__ F, int N,
                             const float* __restrict__ fine,
                             float* __restrict__ out) {
    __shared__ float w[1536];
    __shared__ float bb[3];
    int tid = threadIdx.x;
    for (int l = tid; l < 1536; l += 256) w[l] = Wx[l];
    if (tid < 3) bb[tid] = bx[tid];
    __syncthreads();
    int b = blockIdx.y;
    int n = blockIdx.x * 256 + tid;
    const float* Fb = F + (long)b * 512 * N;
    float a0 = 0.f, a1 = 0.f, a2 = 0.f;
    for (int k = 0; k < 512; ++k) {
        float v = Fb[(long)k * N + n];
        a0 += w[k] * v; a1 += w[512 + k] * v; a2 += w[1024 + k] * v;
    }
    long base = ((long)b * N + n) * 3;
    float d0 = 0.1f * (1.f / (1.f + expf(-(a0 + bb[0]))) - 0.5f);
    float d1 = 0.1f * (1.f / (1.f + expf(-(a1 + bb[1]))) - 0.5f);
    float d2 = 0.1f * (1.f / (1.f + expf(-(a2 + bb[2]))) - 0.5f);
    out[base + 0] = fine[base + 0] + d0;
    out[base + 1] = fine[base + 1] + d1;
    out[base + 2] = fine[base + 2] + d2;
}

// ---------------- transpose h3 (B,512,N2) [featbuf rows 0..511] -> (B,N2,512) ----
__global__ void k_transpose(const float* __restrict__ src, float* __restrict__ dst) {
    __shared__ float t[32][33];
    int tid = threadIdx.x;
    int lx = tid & 31, ly = tid >> 5;   // 32x8
    int n0 = blockIdx.x * 32, c0 = blockIdx.y * 32, b = blockIdx.z;
    const float* sb = src + (long)b * FEAT_BSTR;
    float* db = dst + (long)b * N2 * 512;
    for (int r = ly; r < 32; r += 8) t[r][lx] = sb[(long)(c0 + r) * N2 + n0 + lx];
    __syncthreads();
    for (int r = ly; r < 32; r += 8) db[(long)(n0 + r) * 512 + c0 + lx] = t[lx][r];
}

// ---------------- ball query + gather max ----------------
__global__ __launch_bounds__(256) void k_ball_group(
    const float* __restrict__ fine,      // (B,N2,3)
    const float* __restrict__ hCT,       // (B,N2,512)
    float* __restrict__ featbuf) {       // write rows 512..1023
    int i = blockIdx.x, b = blockIdx.y;
    int tid = threadIdx.x;
    __shared__ unsigned long long segmask[N2 / 64];
    __shared__ int idxl[NSAMPLE];
    __shared__ int mcount;
    const float* fb = fine + (long)b * N2 * 3;
    float xi = fb[i * 3 + 0], yi = fb[i * 3 + 1], zi = fb[i * 3 + 2];
    float sqi = __fadd_rn(__fadd_rn(__fmul_rn(xi, xi), __fmul_rn(yi, yi)), __fmul_rn(zi, zi));
    int wv = tid >> 6, lane = tid & 63;
    #pragma unroll
    for (int it = 0; it < N2 / 256; ++it) {
        int j = it * 256 + tid;
        float xj = fb[j * 3 + 0], yj = fb[j * 3 + 1], zj = fb[j * 3 + 2];
        float sqj = __fadd_rn(__fadd_rn(__fmul_rn(xj, xj), __fmul_rn(yj, yj)), __fmul_rn(zj, zj));
        float dot = __fadd_rn(__fadd_rn(__fmul_rn(xi, xj), __fmul_rn(yi, yj)), __fmul_rn(zi, zj));
        float d2 = __fsub_rn(__fadd_rn(sqi, sqj), __fmul_rn(2.0f, dot));
        unsigned long long m = __ballot(d2 < 0.01f);
        if (lane == 0) segmask[it * 4 + wv] = m;
    }
    __syncthreads();
    if (tid == 0) {
        int m = 0;
        for (int s = 0; s < N2 / 64 && m < NSAMPLE; ++s) {
            unsigned long long mm = segmask[s];
            while (mm && m < NSAMPLE) {
                int bp = __ffsll(mm) - 1;
                idxl[m++] = s * 64 + bp;
                mm &= mm - 1;
            }
        }
        mcount = m;
    }
    __syncthreads();
    int m = mcount;
    const float* hb = hCT + (long)b * N2 * 512;
    float* outb = featbuf + (long)b * FEAT_BSTR;
    for (int c = tid; c < 512; c += 256) {
        float mv = -1e30f;
        for (int jj = 0; jj < m; ++jj) mv = fmaxf(mv, hb[(long)idxl[jj] * 512 + c]);
        outb[(long)(512 + c) * N2 + i] = mv;
    }
}

// ---------------- per-channel global max over N ----------------
__global__ void k_rowmax(const float* __restrict__ src, float* __restrict__ glob) {
    int c = blockIdx.x, b = blockIdx.y;
    int tid = threadIdx.x;
    const float* p = src + (long)b * FEAT_BSTR + (long)c * N2;
    float m = -1e30f;
    for (int n = tid; n < N2; n += 256) m = fmaxf(m, p[n]);
    __shared__ float red[256];
    red[tid] = m;
    __syncthreads();
    for (int s = 128; s > 0; s >>= 1) {
        if (tid < s) red[tid] = fmaxf(red[tid], red[tid + s]);
        __syncthreads();
    }
    if (tid == 0) glob[b * 512 + c] = red[0];
}

// ---------------- launch ----------------
extern "C" void kernel_launch(void* const* d_in, const int* in_sizes, int n_in,
                              void* d_out, int out_size, void* d_ws, size_t ws_size,
                              hipStream_t stream) {
    const float* z   = (const float*)d_in[0];
    const float* W1a = (const float*)d_in[1];
    const float* b1a = (const float*)d_in[2];
    const float* W1b = (const float*)d_in[3];
    const float* b1b = (const float*)d_in[4];
    const float* W1c = (const float*)d_in[5];
    const float* b1c = (const float*)d_in[6];
    const float* Wx1 = (const float*)d_in[7];
    const float* bx1 = (const float*)d_in[8];
    const float* W2a = (const float*)d_in[9];
    const float* b2a = (const float*)d_in[10];
    const float* W2b = (const float*)d_in[11];
    const float* b2b = (const float*)d_in[12];
    const float* W2c = (const float*)d_in[13];
    const float* b2c = (const float*)d_in[14];
    const float* Wx2 = (const float*)d_in[15];
    const float* bx2 = (const float*)d_in[16];

    float* ws = (float*)d_ws;
    float* featbuf = ws + FEAT_OFF;
    float* bufA = ws + BUFA_OFF;
    float* bufB = ws + BUFB_OFF;
    float* c1 = ws + C1_OFF;
    float* glob = ws + GLOB_OFF;
    float* gbias = ws + GBIAS_OFF;

    float* out0 = (float*)d_out;             // (2,1024,3) first_stage_points
    float* out1 = out0 + B * N1 * 3;         // (2,2048,3) second_stage_points
    float* out2 = out1 + B * N2 * 3;         // (2,2048,3) fine_points (also used as fp32 buffer)
    float* fine = out2;

    // c1 = W1a[:, :512] @ z + b1a
    k_c1<<<256, 256, 0, stream>>>(z, W1a, b1a, c1);

    // ---- stage 1 (N1) ----
    k_layer_a<<<B * 512 * N1 / 256, 256, 0, stream>>>(W1a, c1, bufA, N1, SIDE1);
    k_gemm_leaky<<<dim3(N1 / 64, 8, B), 256, 0, stream>>>(W1b, 512, bufA, (long)512 * N1,
                                                          b1b, 0, bufB, (long)512 * N1, 512, N1);
    k_gemm_leaky<<<dim3(N1 / 64, 8, B), 256, 0, stream>>>(W1c, 512, bufB, (long)512 * N1,
                                                          b1c, 0, bufA, (long)512 * N1, 512, N1);
    k_proj_head<<<dim3(N1 / 256, B), 256, 0, stream>>>(Wx1, bx1, bufA, (long)512 * N1, N1, out0);

    // ---- stage 1 (N2) ----
    k_layer_a<<<B * 512 * N2 / 256, 256, 0, stream>>>(W1a, c1, bufA, N2, SIDE2);
    k_gemm_leaky<<<dim3(N2 / 64, 8, B), 256, 0, stream>>>(W1b, 512, bufA, (long)512 * N2,
                                                          b1b, 0, bufB, (long)512 * N2, 512, N2);
    k_gemm_leaky<<<dim3(N2 / 64, 8, B), 256, 0, stream>>>(W1c, 512, bufB, (long)512 * N2,
                                                          b1c, 0, featbuf, (long)FEAT_BSTR, 512, N2);
    k_proj_head<<<dim3(N2 / 256, B), 256, 0, stream>>>(Wx1, bx1, featbuf, (long)FEAT_BSTR, N2, out2);

    // ---- ball group ----
    k_transpose<<<dim3(N2 / 32, 512 / 32, B), 256, 0, stream>>>(featbuf, bufA);
    k_ball_group<<<dim3(N2, B), 256, 0, stream>>>(fine, bufA, featbuf);
    k_rowmax<<<dim3(512, B), 256, 0, stream>>>(featbuf, glob);
    k_gbias<<<256, 256, 0, stream>>>(W2a, b2a, glob, gbias);

    // ---- stage 2 MLP ----
    k_gemm_leaky<<<dim3(N2 / 64, 8, B), 256, 0, stream>>>(W2a, 1536, featbuf, (long)FEAT_BSTR,
                                                          gbias, 512, bufB, (long)512 * N2, 1024, N2);
    k_gemm_leaky<<<dim3(N2 / 64, 8, B), 256, 0, stream>>>(W2b, 512, bufB, (long)512 * N2,
                                                          b2b, 0, bufA, (long)512 * N2, 512, N2);
    k_gemm_leaky<<<dim3(N2 / 64, 8, B), 256, 0, stream>>>(W2c, 512, bufA, (long)512 * N2,
                                                          b2c, 0, bufB, (long)512 * N2, 512, N2);
    k_final_head<<<dim3(N2 / 256, B), 256, 0, stream>>>(Wx2, bx2, bufB, N2, fine, out1);
}

// Round 3
// 340.754 us; speedup vs baseline: 2.5925x; 2.5925x over previous
//
#include <hip/hip_runtime.h>
#include <math.h>

#define B 2
#define N1 1024
#define N2 2048
#define R1TOT 6144   // [b0:N1 | b1:N1 | b0:N2 | b1:N2]
#define R2TOT 4096   // [b0:N2 | b1:N2]
#define SLOPE 0.2f

typedef short bf16x8 __attribute__((ext_vector_type(8)));
typedef float f32x4 __attribute__((ext_vector_type(4)));
typedef unsigned short u16x4 __attribute__((ext_vector_type(4)));

__device__ __forceinline__ unsigned short f2bf(float x) {
    unsigned int u = __float_as_uint(x);
    unsigned int r = (u + 0x7fffu + ((u >> 16) & 1u)) >> 16;   // RNE
    return (unsigned short)r;
}
__device__ __forceinline__ float bf2f(unsigned short h) {
    return __uint_as_float(((unsigned int)h) << 16);
}

// ---------------- pack all 5 weight matrices into [Wh|Wl] bf16 rows ----------------
// layout in wp: W1b,W1c,W2b,W2c (each 512x1024 ushort), then W2a (512x2048 ushort)
__global__ void k_pack_all(const float* __restrict__ W1b, const float* __restrict__ W1c,
                           const float* __restrict__ W2b, const float* __restrict__ W2c,
                           const float* __restrict__ W2a, unsigned short* __restrict__ wp) {
    int idx = blockIdx.x * 256 + threadIdx.x;   // 1,572,864 total
    const float* src; unsigned short* dst; int o, k, K, in_ld;
    if (idx < 1048576) {
        int which = idx >> 18; int local = idx & 262143;
        K = 512; in_ld = 512;
        src = (which == 0) ? W1b : (which == 1) ? W1c : (which == 2) ? W2b : W2c;
        dst = wp + (long)which * 524288;
        o = local >> 9; k = local & 511;
    } else {
        int local = idx - 1048576;
        K = 1024; in_ld = 1536; src = W2a; dst = wp + 2097152;
        o = local >> 10; k = local & 1023;
    }
    float v = src[(long)o * in_ld + k];
    unsigned short hi = f2bf(v);
    dst[(long)o * 2 * K + k] = hi;
    dst[(long)o * 2 * K + K + k] = f2bf(v - bf2f(hi));
}

// ---------------- c1 = W1a[:, :512] @ z + b1a (exact fp32) ----------------
__global__ void k_c1(const float* __restrict__ z, const float* __restrict__ W1a,
                     const float* __restrict__ b1a, float* __restrict__ c1) {
    int gid = blockIdx.x * 4 + (threadIdx.x >> 6);   // 0..1023
    int lane = threadIdx.x & 63;
    int b = gid >> 9, o = gid & 511;
    float acc = 0.f;
    const float* wr = W1a + (long)o * 514;
    const float* zb = z + b * 512;
    for (int k = lane; k < 512; k += 64) acc += wr[k] * zb[k];
    #pragma unroll
    for (int off = 32; off > 0; off >>= 1) acc += __shfl_down(acc, off, 64);
    if (lane == 0) c1[gid] = acc + b1a[o];
}

// ---------------- gbias = W2a[:,1024:1536] @ glob + b2a (exact fp32) ----------------
__global__ void k_gbias(const float* __restrict__ W2a, const float* __restrict__ b2a,
                        const float* __restrict__ glob, float* __restrict__ gbias) {
    int gid = blockIdx.x * 4 + (threadIdx.x >> 6);
    int lane = threadIdx.x & 63;
    int b = gid >> 9, o = gid & 511;
    float acc = 0.f;
    const float* wr = W2a + (long)o * 1536 + 1024;
    const float* gb = glob + b * 512;
    for (int k = lane; k < 512; k += 64) acc += wr[k] * gb[k];
    #pragma unroll
    for (int off = 32; off > 0; off >>= 1) acc += __shfl_down(acc, off, 64);
    if (lane == 0) gbias[gid] = acc + b2a[o];
}

// ---------------- layer 1a: pointwise rank-2 update, emit packed [Xh|Xl] ----------------
__global__ void k_layer_a(const float* __restrict__ W1a, const float* __restrict__ c1,
                          unsigned short* __restrict__ X1) {
    int idx = blockIdx.x * 256 + threadIdx.x;   // 6144*512
    int o = idx & 511;
    int r = idx >> 9;                            // combined row 0..6143
    int b, n, side;
    if (r < 2048) { b = r >> 10; n = r & 1023; side = 32; }
    else          { int r2 = r - 2048; b = r2 >> 11; n = r2 & 2047; side = 46; }
    int row = n / side, col = n % side;
    double inv = 1.0 / (double)(side - 1);
    float lx = (row == side - 1) ? 1.0f : (float)(row * inv);
    float ly = (col == side - 1) ? 1.0f : (float)(col * inv);
    float h = c1[b * 512 + o] + W1a[(long)o * 514 + 512] * lx + W1a[(long)o * 514 + 513] * ly;
    h = (h > 0.f) ? h : SLOPE * h;
    unsigned short hi = f2bf(h);
    X1[(long)r * 1024 + o] = hi;
    X1[(long)r * 1024 + 512 + o] = f2bf(h - bf2f(hi));
}

// ---------------- split-bf16 MFMA GEMM ----------------
// Wp: [512][2K] rows o = [Wh|Wl].  Xp: [R][2K] rows n = [Xh|Xl].
// Y[o][n] = leaky( sum_k W[o][k]*X[n][k] + bias ), via Wh*Xh + Wh*Xl + Wl*Xh.
// Tile 64(o) x 64(n), BK=64, 4 waves in 2x2, each wave 32x32 (2x2 of 16x16x32 MFMA).
// LDS: 4 tiles (Ah,Al,Bh,Bl) of 64x64 bf16, XOR-swizzled chunks: chunk' = chunk ^ (row&7).
__global__ __launch_bounds__(256, 2) void k_gemm(
    const unsigned short* __restrict__ Wp,
    const unsigned short* __restrict__ Xp,
    int K, int R,
    const float* __restrict__ bias, int bias_div,
    float* __restrict__ Yf,            // [512][R] fp32 or null
    float* __restrict__ YfT,           // [R-row_off][512] fp32 or null
    unsigned short* __restrict__ Xn,   // [R-row_off][2*Kn] packed or null
    int Kn, int row_off, int pack_min) {

    __shared__ __align__(16) char sm[32768];
    const int t = threadIdx.x;
    const int nb0 = blockIdx.x * 64;
    const int ob0 = blockIdx.y * 64;
    const int ldk = 2 * K;

    // staging: 8 slots of 256 chunks (16B each): Ah,Ah,Al,Al,Bh,Bh,Bl,Bl halves
    const unsigned short* gp[8];
    int lo_[8];
    #pragma unroll
    for (int p = 0; p < 8; ++p) {
        int T = p >> 1;
        int j2 = ((p & 1) << 8) + t;
        int r = j2 >> 3, cl = j2 & 7, cs = cl ^ (r & 7);
        const unsigned short* base = (T < 2)
            ? (Wp + (long)(ob0 + r) * ldk + ((T == 1) ? K : 0) + cs * 8)
            : (Xp + (long)(nb0 + r) * ldk + ((T == 3) ? K : 0) + cs * 8);
        gp[p] = base;
        lo_[p] = p * 4096 + t * 16;
    }

    const int lane = t & 63, w = t >> 6;
    const int wy = w >> 1, wx = w & 1;
    const int quad = lane >> 4, l15 = lane & 15;
    const int xm = l15 & 7;
    const int rowA = (wy * 32 + l15) * 128;
    const int rowB = (wx * 32 + l15) * 128;
    const int ca0 = (quad ^ xm) * 16;
    const int ca1 = ((quad + 4) ^ xm) * 16;

    f32x4 acc[2][2];
    #pragma unroll
    for (int i = 0; i < 2; ++i)
        #pragma unroll
        for (int j = 0; j < 2; ++j) { f32x4 zz = {0.f, 0.f, 0.f, 0.f}; acc[i][j] = zz; }

    for (int k0 = 0; k0 < K; k0 += 64) {
        #pragma unroll
        for (int p = 0; p < 8; ++p)
            __builtin_amdgcn_global_load_lds(
                (const __attribute__((address_space(1))) void*)(const void*)(gp[p] + k0),
                (__attribute__((address_space(3))) void*)(void*)(sm + lo_[p]),
                16, 0, 0);
        __syncthreads();
        #pragma unroll
        for (int sub = 0; sub < 2; ++sub) {
            const int cb = (sub == 0) ? ca0 : ca1;
            bf16x8 ah[2], al[2], bh[2], bl[2];
            #pragma unroll
            for (int i = 0; i < 2; ++i) {
                ah[i] = *(const bf16x8*)(const void*)(sm +         rowA + i * 2048 + cb);
                al[i] = *(const bf16x8*)(const void*)(sm +  8192 + rowA + i * 2048 + cb);
            }
            #pragma unroll
            for (int j = 0; j < 2; ++j) {
                bh[j] = *(const bf16x8*)(const void*)(sm + 16384 + rowB + j * 2048 + cb);
                bl[j] = *(const bf16x8*)(const void*)(sm + 24576 + rowB + j * 2048 + cb);
            }
            #pragma unroll
            for (int i = 0; i < 2; ++i)
                #pragma unroll
                for (int j = 0; j < 2; ++j) {
                    acc[i][j] = __builtin_amdgcn_mfma_f32_16x16x32_bf16(ah[i], bh[j], acc[i][j], 0, 0, 0);
                    acc[i][j] = __builtin_amdgcn_mfma_f32_16x16x32_bf16(ah[i], bl[j], acc[i][j], 0, 0, 0);
                    acc[i][j] = __builtin_amdgcn_mfma_f32_16x16x32_bf16(al[i], bh[j], acc[i][j], 0, 0, 0);
                }
        }
        __syncthreads();
    }

    // epilogue: bias + leaky, optional fp32 [o][n], fp32T [n][o], packed [Xh|Xl]
    #pragma unroll
    for (int j = 0; j < 2; ++j) {
        int n = nb0 + wx * 32 + j * 16 + l15;
        int bidx0 = (bias_div >= (1 << 29)) ? 0 : (n / bias_div) * 512;
        #pragma unroll
        for (int i = 0; i < 2; ++i) {
            int ob = ob0 + wy * 32 + i * 16 + quad * 4;
            f32x4 v = acc[i][j];
            float vv[4];
            #pragma unroll
            for (int r = 0; r < 4; ++r) {
                float x = v[r] + bias[bidx0 + ob + r];
                vv[r] = (x > 0.f) ? x : SLOPE * x;
            }
            if (Yf) {
                #pragma unroll
                for (int r = 0; r < 4; ++r) Yf[(long)(ob + r) * R + n] = vv[r];
            }
            if (n >= pack_min) {
                int nl = n - row_off;
                if (YfT) {
                    f32x4 tv = {vv[0], vv[1], vv[2], vv[3]};
                    *(f32x4*)(void*)(YfT + (long)nl * 512 + ob) = tv;
                }
                if (Xn) {
                    u16x4 h4, l4;
                    #pragma unroll
                    for (int r = 0; r < 4; ++r) {
                        unsigned short hb = f2bf(vv[r]);
                        h4[r] = hb;
                        l4[r] = f2bf(vv[r] - bf2f(hb));
                    }
                    unsigned short* rowp = Xn + (long)nl * (2 * Kn);
                    *(u16x4*)(void*)(rowp + ob) = h4;
                    *(u16x4*)(void*)(rowp + Kn + ob) = l4;
                }
            }
        }
    }
}

// ---------------- head: sigmoid projection (proj: out=s-0.5; final: out=fine+0.1*s) ----
__global__ void k_head(const float* __restrict__ Wx, const float* __restrict__ bx,
                       const float* __restrict__ H, int R, int col0, int N,
                       float* __restrict__ out, const float* __restrict__ fine) {
    __shared__ float wsm[1536];
    __shared__ float bb[3];
    int tid = threadIdx.x;
    for (int l = tid; l < 1536; l += 256) wsm[l] = Wx[l];
    if (tid < 3) bb[tid] = bx[tid];
    __syncthreads();
    int b = blockIdx.y;
    int n = blockIdx.x * 256 + tid;
    const float* Hc = H + col0 + (long)b * N + n;
    float a0 = 0.f, a1 = 0.f, a2 = 0.f;
    #pragma unroll 8
    for (int k = 0; k < 512; ++k) {
        float v = Hc[(long)k * R];
        a0 += wsm[k] * v; a1 += wsm[512 + k] * v; a2 += wsm[1024 + k] * v;
    }
    float s0 = 1.f / (1.f + expf(-(a0 + bb[0]))) - 0.5f;
    float s1 = 1.f / (1.f + expf(-(a1 + bb[1]))) - 0.5f;
    float s2 = 1.f / (1.f + expf(-(a2 + bb[2]))) - 0.5f;
    long base = ((long)b * N + n) * 3;
    if (fine) {
        out[base + 0] = fine[base + 0] + 0.1f * s0;
        out[base + 1] = fine[base + 1] + 0.1f * s1;
        out[base + 2] = fine[base + 2] + 0.1f * s2;
    } else {
        out[base + 0] = s0; out[base + 1] = s1; out[base + 2] = s2;
    }
}

// ---------------- ball query + gather-max, emit packed local into X2P ----------------
__global__ __launch_bounds__(256) void k_ball(const float* __restrict__ fine,
                                              const float* __restrict__ h3T,
                                              unsigned short* __restrict__ X2P) {
    int i = blockIdx.x, b = blockIdx.y;
    int tid = threadIdx.x;
    __shared__ unsigned long long segmask[N2 / 64];
    __shared__ int idxl[64];
    __shared__ int mcount;
    const float* fb = fine + (long)b * N2 * 3;
    float xi = fb[i * 3 + 0], yi = fb[i * 3 + 1], zi = fb[i * 3 + 2];
    float sqi = __fadd_rn(__fadd_rn(__fmul_rn(xi, xi), __fmul_rn(yi, yi)), __fmul_rn(zi, zi));
    int wv = tid >> 6, lane = tid & 63;
    #pragma unroll
    for (int it = 0; it < N2 / 256; ++it) {
        int j = it * 256 + tid;
        float xj = fb[j * 3 + 0], yj = fb[j * 3 + 1], zj = fb[j * 3 + 2];
        float sqj = __fadd_rn(__fadd_rn(__fmul_rn(xj, xj), __fmul_rn(yj, yj)), __fmul_rn(zj, zj));
        float dot = __fadd_rn(__fadd_rn(__fmul_rn(xi, xj), __fmul_rn(yi, yj)), __fmul_rn(zi, zj));
        float d2 = __fsub_rn(__fadd_rn(sqi, sqj), __fmul_rn(2.0f, dot));
        unsigned long long m = __ballot(d2 < 0.01f);
        if (lane == 0) segmask[it * 4 + wv] = m;
    }
    __syncthreads();
    if (tid == 0) {
        int m = 0;
        for (int s = 0; s < N2 / 64 && m < 64; ++s) {
            unsigned long long mm = segmask[s];
            while (mm && m < 64) {
                int bp = __ffsll(mm) - 1;
                idxl[m++] = s * 64 + bp;
                mm &= mm - 1;
            }
        }
        mcount = m;
    }
    __syncthreads();
    int m = mcount;
    const float* hb = h3T + (long)b * N2 * 512;
    unsigned short* orow = X2P + (long)(b * N2 + i) * 2048;
    for (int c = tid; c < 512; c += 256) {
        float mv = -1e30f;
        for (int jj = 0; jj < m; ++jj) mv = fmaxf(mv, hb[(long)idxl[jj] * 512 + c]);
        unsigned short hi = f2bf(mv);
        orow[512 + c] = hi;
        orow[1536 + c] = f2bf(mv - bf2f(hi));
    }
}

// ---------------- per-channel global max over the N2 columns of Y1 ----------------
__global__ void k_rowmax(const float* __restrict__ Y1, float* __restrict__ glob) {
    int c = blockIdx.x, b = blockIdx.y;
    int tid = threadIdx.x;
    const float* p = Y1 + (long)c * R1TOT + 2048 + b * N2;
    float mx = -1e30f;
    for (int n = tid; n < N2; n += 256) mx = fmaxf(mx, p[n]);
    __shared__ float red[256];
    red[tid] = mx;
    __syncthreads();
    for (int s = 128; s > 0; s >>= 1) {
        if (tid < s) red[tid] = fmaxf(red[tid], red[tid + s]);
        __syncthreads();
    }
    if (tid == 0) glob[b * 512 + c] = red[0];
}

// ---------------- launch ----------------
extern "C" void kernel_launch(void* const* d_in, const int* in_sizes, int n_in,
                              void* d_out, int out_size, void* d_ws, size_t ws_size,
                              hipStream_t stream) {
    const float* z   = (const float*)d_in[0];
    const float* W1a = (const float*)d_in[1];
    const float* b1a = (const float*)d_in[2];
    const float* W1b = (const float*)d_in[3];
    const float* b1b = (const float*)d_in[4];
    const float* W1c = (const float*)d_in[5];
    const float* b1c = (const float*)d_in[6];
    const float* Wx1 = (const float*)d_in[7];
    const float* bx1 = (const float*)d_in[8];
    const float* W2a = (const float*)d_in[9];
    const float* b2a = (const float*)d_in[10];
    const float* W2b = (const float*)d_in[11];
    const float* b2b = (const float*)d_in[12];
    const float* W2c = (const float*)d_in[13];
    const float* b2c = (const float*)d_in[14];
    const float* Wx2 = (const float*)d_in[15];
    const float* bx2 = (const float*)d_in[16];

    // ---- workspace layout (bytes) ----
    char* wsb = (char*)d_ws;
    unsigned short* WP  = (unsigned short*)(wsb + 0);          //  6,291,456 B (5 packed weights)
    unsigned short* X1P = (unsigned short*)(wsb + 6291456);    // 12,582,912 B [6144][1024]
    unsigned short* XMP = (unsigned short*)(wsb + 18874368);   // 12,582,912 B [6144][1024]
    unsigned short* X2P = (unsigned short*)(wsb + 31457280);   // 16,777,216 B [4096][2048]
    float*          H3T = (float*)(wsb + 48234496);            //  8,388,608 B [4096][512]
    unsigned short* X3P = (unsigned short*)(wsb + 48234496);   //  alias H3T  [4096][1024]
    float*          Y1  = (float*)(wsb + 56623104);            // 12,582,912 B [512][6144]
    float*          Y2  = (float*)(wsb + 56623104);            //  alias Y1   [512][4096]
    unsigned short* X4P = X1P;                                 //  alias X1P  [4096][1024]
    float* c1    = (float*)(wsb + 69206016);
    float* glob  = (float*)(wsb + 69210112);
    float* gbias = (float*)(wsb + 69214208);

    unsigned short* WP1b = WP;
    unsigned short* WP1c = WP + 524288;
    unsigned short* WP2b = WP + 1048576;
    unsigned short* WP2c = WP + 1572864;
    unsigned short* WP2a = WP + 2097152;

    float* out0 = (float*)d_out;          // (2,1024,3) first_stage_points
    float* out1 = out0 + B * N1 * 3;      // (2,2048,3) second_stage_points
    float* out2 = out1 + B * N2 * 3;      // (2,2048,3) fine_points
    float* fine = out2;

    const int BIG = 1 << 30;

    k_pack_all<<<6144, 256, 0, stream>>>(W1b, W1c, W2b, W2c, W2a, WP);
    k_c1<<<256, 256, 0, stream>>>(z, W1a, b1a, c1);
    k_layer_a<<<12288, 256, 0, stream>>>(W1a, c1, X1P);

    // stage-1 MLP (N1+N2 fused, 6144 rows)
    k_gemm<<<dim3(96, 8), 256, 0, stream>>>(WP1b, X1P, 512, R1TOT, b1b, BIG,
                                            nullptr, nullptr, XMP, 512, 0, 0);
    k_gemm<<<dim3(96, 8), 256, 0, stream>>>(WP1c, XMP, 512, R1TOT, b1c, BIG,
                                            Y1, H3T, X2P, 1024, 2048, 2048);
    k_head<<<dim3(4, 2), 256, 0, stream>>>(Wx1, bx1, Y1, R1TOT, 0,    N1, out0, nullptr);
    k_head<<<dim3(8, 2), 256, 0, stream>>>(Wx1, bx1, Y1, R1TOT, 2048, N2, out2, nullptr);

    // ball grouping + global max
    k_ball<<<dim3(N2, B), 256, 0, stream>>>(fine, H3T, X2P);
    k_rowmax<<<dim3(512, B), 256, 0, stream>>>(Y1, glob);
    k_gbias<<<256, 256, 0, stream>>>(W2a, b2a, glob, gbias);

    // stage-2 MLP (4096 rows)
    k_gemm<<<dim3(64, 8), 256, 0, stream>>>(WP2a, X2P, 1024, R2TOT, gbias, 2048,
                                            nullptr, nullptr, X3P, 512, 0, 0);
    k_gemm<<<dim3(64, 8), 256, 0, stream>>>(WP2b, X3P, 512, R2TOT, b2b, BIG,
                                            nullptr, nullptr, X4P, 512, 0, 0);
    k_gemm<<<dim3(64, 8), 256, 0, stream>>>(WP2c, X4P, 512, R2TOT, b2c, BIG,
                                            Y2, nullptr, nullptr, 0, 0, 0);
    k_head<<<dim3(8, 2), 256, 0, stream>>>(Wx2, bx2, Y2, R2TOT, 0, N2, out1, fine);
}

// Round 4
// 290.776 us; speedup vs baseline: 3.0381x; 1.1719x over previous
//
#include <hip/hip_runtime.h>
#include <math.h>

#define B 2
#define N1 1024
#define N2 2048
#define R1TOT 6144   // [b0:N1 | b1:N1 | b0:N2 | b1:N2]
#define R2TOT 4096   // [b0:N2 | b1:N2]
#define SLOPE 0.2f

typedef short bf16x8 __attribute__((ext_vector_type(8)));
typedef float f32x4 __attribute__((ext_vector_type(4)));
typedef unsigned short u16x4 __attribute__((ext_vector_type(4)));
typedef unsigned short u16x8 __attribute__((ext_vector_type(8)));

__device__ __forceinline__ unsigned short f2bf(float x) {
    unsigned int u = __float_as_uint(x);
    unsigned int r = (u + 0x7fffu + ((u >> 16) & 1u)) >> 16;   // RNE
    return (unsigned short)r;
}
__device__ __forceinline__ float bf2f(unsigned short h) {
    return __uint_as_float(((unsigned int)h) << 16);
}

// ---------------- pack all 5 weight matrices into [Wh|Wl] bf16 rows ----------------
__global__ void k_pack_all(const float* __restrict__ W1b, const float* __restrict__ W1c,
                           const float* __restrict__ W2b, const float* __restrict__ W2c,
                           const float* __restrict__ W2a, unsigned short* __restrict__ wp) {
    int idx = blockIdx.x * 256 + threadIdx.x;   // 1,572,864 total
    const float* src; unsigned short* dst; int o, k, K, in_ld;
    if (idx < 1048576) {
        int which = idx >> 18; int local = idx & 262143;
        K = 512; in_ld = 512;
        src = (which == 0) ? W1b : (which == 1) ? W1c : (which == 2) ? W2b : W2c;
        dst = wp + (long)which * 524288;
        o = local >> 9; k = local & 511;
    } else {
        int local = idx - 1048576;
        K = 1024; in_ld = 1536; src = W2a; dst = wp + 2097152;
        o = local >> 10; k = local & 1023;
    }
    float v = src[(long)o * in_ld + k];
    unsigned short hi = f2bf(v);
    dst[(long)o * 2 * K + k] = hi;
    dst[(long)o * 2 * K + K + k] = f2bf(v - bf2f(hi));
}

// ---------------- c1 = W1a[:, :512] @ z + b1a (exact fp32) ----------------
__global__ void k_c1(const float* __restrict__ z, const float* __restrict__ W1a,
                     const float* __restrict__ b1a, float* __restrict__ c1) {
    int gid = blockIdx.x * 4 + (threadIdx.x >> 6);   // 0..1023
    int lane = threadIdx.x & 63;
    int b = gid >> 9, o = gid & 511;
    float acc = 0.f;
    const float* wr = W1a + (long)o * 514;
    const float* zb = z + b * 512;
    for (int k = lane; k < 512; k += 64) acc += wr[k] * zb[k];
    #pragma unroll
    for (int off = 32; off > 0; off >>= 1) acc += __shfl_down(acc, off, 64);
    if (lane == 0) c1[gid] = acc + b1a[o];
}

// ---------------- gbias = W2a[:,1024:1536] @ glob + b2a (exact fp32) ----------------
__global__ void k_gbias(const float* __restrict__ W2a, const float* __restrict__ b2a,
                        const float* __restrict__ glob, float* __restrict__ gbias) {
    int gid = blockIdx.x * 4 + (threadIdx.x >> 6);
    int lane = threadIdx.x & 63;
    int b = gid >> 9, o = gid & 511;
    float acc = 0.f;
    const float* wr = W2a + (long)o * 1536 + 1024;
    const float* gb = glob + b * 512;
    for (int k = lane; k < 512; k += 64) acc += wr[k] * gb[k];
    #pragma unroll
    for (int off = 32; off > 0; off >>= 1) acc += __shfl_down(acc, off, 64);
    if (lane == 0) gbias[gid] = acc + b2a[o];
}

// ---------------- layer 1a: pointwise rank-2 update, emit packed [Xh|Xl] ----------------
__global__ void k_layer_a(const float* __restrict__ W1a, const float* __restrict__ c1,
                          unsigned short* __restrict__ X1) {
    int idx = blockIdx.x * 256 + threadIdx.x;   // 6144*512
    int o = idx & 511;
    int r = idx >> 9;                            // combined row 0..6143
    int b, n, side;
    if (r < 2048) { b = r >> 10; n = r & 1023; side = 32; }
    else          { int r2 = r - 2048; b = r2 >> 11; n = r2 & 2047; side = 46; }
    int row = n / side, col = n % side;
    double inv = 1.0 / (double)(side - 1);
    float lx = (row == side - 1) ? 1.0f : (float)(row * inv);
    float ly = (col == side - 1) ? 1.0f : (float)(col * inv);
    float h = c1[b * 512 + o] + W1a[(long)o * 514 + 512] * lx + W1a[(long)o * 514 + 513] * ly;
    h = (h > 0.f) ? h : SLOPE * h;
    unsigned short hi = f2bf(h);
    X1[(long)r * 1024 + o] = hi;
    X1[(long)r * 1024 + 512 + o] = f2bf(h - bf2f(hi));
}

// ---------------- split-bf16 MFMA GEMM ----------------
// Wp: [512][2K] rows o = [Wh|Wl].  Xp: [R][2K] rows n = [Xh|Xl].
// Y[o][n] = leaky( sum_k W[o][k]*X[n][k] + bias ), via Wh*Xh + Wh*Xl + Wl*Xh.
__global__ __launch_bounds__(256, 2) void k_gemm(
    const unsigned short* __restrict__ Wp,
    const unsigned short* __restrict__ Xp,
    int K, int R,
    const float* __restrict__ bias, int bias_div,
    float* __restrict__ Yf,            // [512][R] fp32 or null
    unsigned short* __restrict__ YfT,  // [R-row_off][512] bf16-hi or null
    unsigned short* __restrict__ Xn,   // [R-row_off][2*Kn] packed or null
    int Kn, int row_off, int pack_min) {

    __shared__ __align__(16) char sm[32768];
    const int t = threadIdx.x;
    const int nb0 = blockIdx.x * 64;
    const int ob0 = blockIdx.y * 64;
    const int ldk = 2 * K;

    // staging: 8 slots of 256 chunks (16B each): Ah,Ah,Al,Al,Bh,Bh,Bl,Bl halves
    const unsigned short* gp[8];
    int lo_[8];
    #pragma unroll
    for (int p = 0; p < 8; ++p) {
        int T = p >> 1;
        int j2 = ((p & 1) << 8) + t;
        int r = j2 >> 3, cl = j2 & 7, cs = cl ^ (r & 7);
        const unsigned short* base = (T < 2)
            ? (Wp + (long)(ob0 + r) * ldk + ((T == 1) ? K : 0) + cs * 8)
            : (Xp + (long)(nb0 + r) * ldk + ((T == 3) ? K : 0) + cs * 8);
        gp[p] = base;
        lo_[p] = p * 4096 + t * 16;
    }

    const int lane = t & 63, w = t >> 6;
    const int wy = w >> 1, wx = w & 1;
    const int quad = lane >> 4, l15 = lane & 15;
    const int xm = l15 & 7;
    const int rowA = (wy * 32 + l15) * 128;
    const int rowB = (wx * 32 + l15) * 128;
    const int ca0 = (quad ^ xm) * 16;
    const int ca1 = ((quad + 4) ^ xm) * 16;

    f32x4 acc[2][2];
    #pragma unroll
    for (int i = 0; i < 2; ++i)
        #pragma unroll
        for (int j = 0; j < 2; ++j) { f32x4 zz = {0.f, 0.f, 0.f, 0.f}; acc[i][j] = zz; }

    for (int k0 = 0; k0 < K; k0 += 64) {
        #pragma unroll
        for (int p = 0; p < 8; ++p)
            __builtin_amdgcn_global_load_lds(
                (const __attribute__((address_space(1))) void*)(const void*)(gp[p] + k0),
                (__attribute__((address_space(3))) void*)(void*)(sm + lo_[p]),
                16, 0, 0);
        __syncthreads();
        #pragma unroll
        for (int sub = 0; sub < 2; ++sub) {
            const int cb = (sub == 0) ? ca0 : ca1;
            bf16x8 ah[2], al[2], bh[2], bl[2];
            #pragma unroll
            for (int i = 0; i < 2; ++i) {
                ah[i] = *(const bf16x8*)(const void*)(sm +         rowA + i * 2048 + cb);
                al[i] = *(const bf16x8*)(const void*)(sm +  8192 + rowA + i * 2048 + cb);
            }
            #pragma unroll
            for (int j = 0; j < 2; ++j) {
                bh[j] = *(const bf16x8*)(const void*)(sm + 16384 + rowB + j * 2048 + cb);
                bl[j] = *(const bf16x8*)(const void*)(sm + 24576 + rowB + j * 2048 + cb);
            }
            #pragma unroll
            for (int i = 0; i < 2; ++i)
                #pragma unroll
                for (int j = 0; j < 2; ++j) {
                    acc[i][j] = __builtin_amdgcn_mfma_f32_16x16x32_bf16(ah[i], bh[j], acc[i][j], 0, 0, 0);
                    acc[i][j] = __builtin_amdgcn_mfma_f32_16x16x32_bf16(ah[i], bl[j], acc[i][j], 0, 0, 0);
                    acc[i][j] = __builtin_amdgcn_mfma_f32_16x16x32_bf16(al[i], bh[j], acc[i][j], 0, 0, 0);
                }
        }
        __syncthreads();
    }

    // epilogue: bias + leaky, optional fp32 [o][n], bf16T [n][o], packed [Xh|Xl]
    #pragma unroll
    for (int j = 0; j < 2; ++j) {
        int n = nb0 + wx * 32 + j * 16 + l15;
        int bidx0 = (bias_div >= (1 << 29)) ? 0 : (n / bias_div) * 512;
        #pragma unroll
        for (int i = 0; i < 2; ++i) {
            int ob = ob0 + wy * 32 + i * 16 + quad * 4;
            f32x4 v = acc[i][j];
            float vv[4];
            #pragma unroll
            for (int r = 0; r < 4; ++r) {
                float x = v[r] + bias[bidx0 + ob + r];
                vv[r] = (x > 0.f) ? x : SLOPE * x;
            }
            if (Yf) {
                #pragma unroll
                for (int r = 0; r < 4; ++r) Yf[(long)(ob + r) * R + n] = vv[r];
            }
            if (n >= pack_min) {
                int nl = n - row_off;
                if (YfT) {
                    u16x4 t4;
                    #pragma unroll
                    for (int r = 0; r < 4; ++r) t4[r] = f2bf(vv[r]);
                    *(u16x4*)(void*)(YfT + (long)nl * 512 + ob) = t4;
                }
                if (Xn) {
                    u16x4 h4, l4;
                    #pragma unroll
                    for (int r = 0; r < 4; ++r) {
                        unsigned short hb = f2bf(vv[r]);
                        h4[r] = hb;
                        l4[r] = f2bf(vv[r] - bf2f(hb));
                    }
                    unsigned short* rowp = Xn + (long)nl * (2 * Kn);
                    *(u16x4*)(void*)(rowp + ob) = h4;
                    *(u16x4*)(void*)(rowp + Kn + ob) = l4;
                }
            }
        }
    }
}

// ---------------- head: sigmoid projection (proj: out=s-0.5; final: out=fine+0.1*s) ----
__global__ void k_head(const float* __restrict__ Wx, const float* __restrict__ bx,
                       const float* __restrict__ H, int R, int col0, int N,
                       float* __restrict__ out, const float* __restrict__ fine) {
    __shared__ float wsm[1536];
    __shared__ float bb[3];
    int tid = threadIdx.x;
    for (int l = tid; l < 1536; l += 256) wsm[l] = Wx[l];
    if (tid < 3) bb[tid] = bx[tid];
    __syncthreads();
    int b = blockIdx.y;
    int n = blockIdx.x * 256 + tid;
    const float* Hc = H + col0 + (long)b * N + n;
    float a0 = 0.f, a1 = 0.f, a2 = 0.f;
    #pragma unroll 8
    for (int k = 0; k < 512; ++k) {
        float v = Hc[(long)k * R];
        a0 += wsm[k] * v; a1 += wsm[512 + k] * v; a2 += wsm[1024 + k] * v;
    }
    float s0 = 1.f / (1.f + expf(-(a0 + bb[0]))) - 0.5f;
    float s1 = 1.f / (1.f + expf(-(a1 + bb[1]))) - 0.5f;
    float s2 = 1.f / (1.f + expf(-(a2 + bb[2]))) - 0.5f;
    long base = ((long)b * N + n) * 3;
    if (fine) {
        out[base + 0] = fine[base + 0] + 0.1f * s0;
        out[base + 1] = fine[base + 1] + 0.1f * s1;
        out[base + 2] = fine[base + 2] + 0.1f * s2;
    } else {
        out[base + 0] = s0; out[base + 1] = s1; out[base + 2] = s2;
    }
}

// ---------------- ball query (parallel compaction) + bf16 gather-max ----------------
__global__ __launch_bounds__(256) void k_ball(const float* __restrict__ fine,
                                              const unsigned short* __restrict__ h3B,
                                              unsigned short* __restrict__ X2P) {
    int i = blockIdx.x, b = blockIdx.y;
    int tid = threadIdx.x, lane = tid & 63, wv = tid >> 6;
    __shared__ int idxl[64];
    __shared__ int wcnt[4];
    __shared__ float part[8][256];
    const float* fb = fine + (long)b * N2 * 3;
    float xi = fb[i * 3 + 0], yi = fb[i * 3 + 1], zi = fb[i * 3 + 2];
    float sqi = __fadd_rn(__fadd_rn(__fmul_rn(xi, xi), __fmul_rn(yi, yi)), __fmul_rn(zi, zi));
    int cnt = 0;
    for (int it = 0; it < N2 / 256; ++it) {
        int j = it * 256 + tid;
        float xj = fb[j * 3 + 0], yj = fb[j * 3 + 1], zj = fb[j * 3 + 2];
        float sqj = __fadd_rn(__fadd_rn(__fmul_rn(xj, xj), __fmul_rn(yj, yj)), __fmul_rn(zj, zj));
        float dot = __fadd_rn(__fadd_rn(__fmul_rn(xi, xj), __fmul_rn(yi, yj)), __fmul_rn(zi, zj));
        float d2 = __fsub_rn(__fadd_rn(sqi, sqj), __fmul_rn(2.0f, dot));
        bool pred = d2 < 0.01f;
        unsigned long long m = __ballot(pred);
        if (lane == 0) wcnt[wv] = __popcll(m);
        __syncthreads();
        int wbase = cnt;
        #pragma unroll
        for (int q = 0; q < 3; ++q) { if (q < wv) wbase += wcnt[q]; }
        int total = wcnt[0] + wcnt[1] + wcnt[2] + wcnt[3];
        int rank = wbase + __popcll(m & ((1ull << lane) - 1ull));
        if (pred && rank < 64) idxl[rank] = j;
        cnt += total;
        if (cnt >= 64) break;       // uniform across block
        __syncthreads();
    }
    __syncthreads();
    int m = min(cnt, 64);

    // gather: 64 channel-groups (8ch, 16B) x 4 neighbor-quarters
    const unsigned short* hb = h3B + (long)b * N2 * 512;
    int g = tid & 63, q = tid >> 6;
    float mx[8];
    #pragma unroll
    for (int r = 0; r < 8; ++r) mx[r] = -1e30f;
    for (int jj = q; jj < m; jj += 4) {
        u16x8 v = *(const u16x8*)(const void*)(hb + (long)idxl[jj] * 512 + g * 8);
        #pragma unroll
        for (int r = 0; r < 8; ++r) mx[r] = fmaxf(mx[r], bf2f(v[r]));
    }
    #pragma unroll
    for (int r = 0; r < 8; ++r) part[r][tid] = mx[r];
    __syncthreads();
    if (tid < 64) {
        unsigned short* orow = X2P + (long)(b * N2 + i) * 2048;
        u16x8 hi, zz;
        #pragma unroll
        for (int r = 0; r < 8; ++r) {
            float v0 = fmaxf(fmaxf(part[r][tid], part[r][tid + 64]),
                             fmaxf(part[r][tid + 128], part[r][tid + 192]));
            hi[r] = (unsigned short)(__float_as_uint(v0) >> 16);   // exact: v0 is bf16-valued
            zz[r] = 0;
        }
        *(u16x8*)(void*)(orow + 512 + tid * 8) = hi;
        *(u16x8*)(void*)(orow + 1536 + tid * 8) = zz;
    }
}

// ---------------- per-channel global max over the N2 columns of Y1 ----------------
__global__ void k_rowmax(const float* __restrict__ Y1, float* __restrict__ glob) {
    int c = blockIdx.x, b = blockIdx.y;
    int tid = threadIdx.x;
    const float* p = Y1 + (long)c * R1TOT + 2048 + b * N2;
    float mx = -1e30f;
    for (int n = tid; n < N2; n += 256) mx = fmaxf(mx, p[n]);
    __shared__ float red[256];
    red[tid] = mx;
    __syncthreads();
    for (int s = 128; s > 0; s >>= 1) {
        if (tid < s) red[tid] = fmaxf(red[tid], red[tid + s]);
        __syncthreads();
    }
    if (tid == 0) glob[b * 512 + c] = red[0];
}

// ---------------- launch ----------------
extern "C" void kernel_launch(void* const* d_in, const int* in_sizes, int n_in,
                              void* d_out, int out_size, void* d_ws, size_t ws_size,
                              hipStream_t stream) {
    const float* z   = (const float*)d_in[0];
    const float* W1a = (const float*)d_in[1];
    const float* b1a = (const float*)d_in[2];
    const float* W1b = (const float*)d_in[3];
    const float* b1b = (const float*)d_in[4];
    const float* W1c = (const float*)d_in[5];
    const float* b1c = (const float*)d_in[6];
    const float* Wx1 = (const float*)d_in[7];
    const float* bx1 = (const float*)d_in[8];
    const float* W2a = (const float*)d_in[9];
    const float* b2a = (const float*)d_in[10];
    const float* W2b = (const float*)d_in[11];
    const float* b2b = (const float*)d_in[12];
    const float* W2c = (const float*)d_in[13];
    const float* b2c = (const float*)d_in[14];
    const float* Wx2 = (const float*)d_in[15];
    const float* bx2 = (const float*)d_in[16];

    // ---- workspace layout (bytes) ----
    char* wsb = (char*)d_ws;
    unsigned short* WP  = (unsigned short*)(wsb + 0);          //  6,291,456 B (5 packed weights)
    unsigned short* X1P = (unsigned short*)(wsb + 6291456);    // 12,582,912 B [6144][1024]
    unsigned short* XMP = (unsigned short*)(wsb + 18874368);   // 12,582,912 B [6144][1024]
    unsigned short* X2P = (unsigned short*)(wsb + 31457280);   // 16,777,216 B [4096][2048]
    unsigned short* H3B = (unsigned short*)(wsb + 48234496);   //  4,194,304 B [4096][512] bf16-hi
    unsigned short* X3P = (unsigned short*)(wsb + 48234496);   //  alias H3B  [4096][1024] (h3B dead by then)
    float*          Y1  = (float*)(wsb + 56623104);            // 12,582,912 B [512][6144]
    float*          Y2  = (float*)(wsb + 56623104);            //  alias Y1   [512][4096]
    unsigned short* X4P = X1P;                                 //  alias X1P  [4096][1024]
    float* c1    = (float*)(wsb + 69206016);
    float* glob  = (float*)(wsb + 69210112);
    float* gbias = (float*)(wsb + 69214208);

    unsigned short* WP1b = WP;
    unsigned short* WP1c = WP + 524288;
    unsigned short* WP2b = WP + 1048576;
    unsigned short* WP2c = WP + 1572864;
    unsigned short* WP2a = WP + 2097152;

    float* out0 = (float*)d_out;          // (2,1024,3) first_stage_points
    float* out1 = out0 + B * N1 * 3;      // (2,2048,3) second_stage_points
    float* out2 = out1 + B * N2 * 3;      // (2,2048,3) fine_points
    float* fine = out2;

    const int BIG = 1 << 30;

    k_pack_all<<<6144, 256, 0, stream>>>(W1b, W1c, W2b, W2c, W2a, WP);
    k_c1<<<256, 256, 0, stream>>>(z, W1a, b1a, c1);
    k_layer_a<<<12288, 256, 0, stream>>>(W1a, c1, X1P);

    // stage-1 MLP (N1+N2 fused, 6144 rows)
    k_gemm<<<dim3(96, 8), 256, 0, stream>>>(WP1b, X1P, 512, R1TOT, b1b, BIG,
                                            nullptr, nullptr, XMP, 512, 0, 0);
    k_gemm<<<dim3(96, 8), 256, 0, stream>>>(WP1c, XMP, 512, R1TOT, b1c, BIG,
                                            Y1, H3B, X2P, 1024, 2048, 2048);
    k_head<<<dim3(4, 2), 256, 0, stream>>>(Wx1, bx1, Y1, R1TOT, 0,    N1, out0, nullptr);
    k_head<<<dim3(8, 2), 256, 0, stream>>>(Wx1, bx1, Y1, R1TOT, 2048, N2, out2, nullptr);

    // ball grouping + global max
    k_ball<<<dim3(N2, B), 256, 0, stream>>>(fine, H3B, X2P);
    k_rowmax<<<dim3(512, B), 256, 0, stream>>>(Y1, glob);
    k_gbias<<<256, 256, 0, stream>>>(W2a, b2a, glob, gbias);

    // stage-2 MLP (4096 rows)
    k_gemm<<<dim3(64, 8), 256, 0, stream>>>(WP2a, X2P, 1024, R2TOT, gbias, 2048,
                                            nullptr, nullptr, X3P, 512, 0, 0);
    k_gemm<<<dim3(64, 8), 256, 0, stream>>>(WP2b, X3P, 512, R2TOT, b2b, BIG,
                                            nullptr, nullptr, X4P, 512, 0, 0);
    k_gemm<<<dim3(64, 8), 256, 0, stream>>>(WP2c, X4P, 512, R2TOT, b2c, BIG,
                                            Y2, nullptr, nullptr, 0, 0, 0);
    k_head<<<dim3(8, 2), 256, 0, stream>>>(Wx2, bx2, Y2, R2TOT, 0, N2, out1, fine);
}

// Round 5
// 209.035 us; speedup vs baseline: 4.2261x; 1.3910x over previous
//
#include <hip/hip_runtime.h>
#include <math.h>

#define B 2
#define N1 1024
#define N2 2048
#define R1TOT 6144   // [b0:N1 | b1:N1 | b0:N2 | b1:N2]
#define R2TOT 4096   // [b0:N2 | b1:N2]
#define SLOPE 0.2f

typedef short bf16x8 __attribute__((ext_vector_type(8)));
typedef float f32x4 __attribute__((ext_vector_type(4)));
typedef unsigned short u16x4 __attribute__((ext_vector_type(4)));
typedef unsigned short u16x8 __attribute__((ext_vector_type(8)));

__device__ __forceinline__ unsigned short f2bf(float x) {
    unsigned int u = __float_as_uint(x);
    unsigned int r = (u + 0x7fffu + ((u >> 16) & 1u)) >> 16;   // RNE
    return (unsigned short)r;
}
__device__ __forceinline__ float bf2f(unsigned short h) {
    return __uint_as_float(((unsigned int)h) << 16);
}
// order-preserving float<->u32 (for atomicMax)
__device__ __forceinline__ unsigned fenc(float f) {
    unsigned u = __float_as_uint(f);
    return (u & 0x80000000u) ? ~u : (u | 0x80000000u);
}
__device__ __forceinline__ float fdec(unsigned u) {
    unsigned b = (u & 0x80000000u) ? (u & 0x7FFFFFFFu) : ~u;
    return __uint_as_float(b);
}

// ---- ws byte offsets ----
#define OFF_WP     0
#define OFF_X1P    6291456
#define OFF_XMP    18874368
#define OFF_X2P    31457280
#define OFF_X3P    39845888
#define OFF_X4P    44040192
#define OFF_C1     48234496
#define OFF_GLOBE  48238592
#define OFF_GBIAS  48242688
#define OFF_HACC1  48246784   // [6144][4] f32
#define OFF_HACC2  48345088   // [4096][4] f32
#define ZERO_WORDS 43008      // globE..hacc2 end

// ---------------- prep: pack weights + zero accumulators + c1 GEMV ----------------
__global__ void k_prep(const float* __restrict__ W1b, const float* __restrict__ W1c,
                       const float* __restrict__ W2b, const float* __restrict__ W2c,
                       const float* __restrict__ W2a, unsigned short* __restrict__ wp,
                       const float* __restrict__ z, const float* __restrict__ W1a,
                       const float* __restrict__ b1a, float* __restrict__ c1,
                       float* __restrict__ zbase) {
    int bx = blockIdx.x, tid = threadIdx.x;
    if (bx < 6144) {
        int idx = bx * 256 + tid;
        const float* src; unsigned short* dst; int o, k, K, in_ld;
        if (idx < 1048576) {
            int which = idx >> 18; int local = idx & 262143;
            K = 512; in_ld = 512;
            src = (which == 0) ? W1b : (which == 1) ? W1c : (which == 2) ? W2b : W2c;
            dst = wp + (long)which * 524288;
            o = local >> 9; k = local & 511;
        } else {
            int local = idx - 1048576;
            K = 1024; in_ld = 1536; src = W2a; dst = wp + 2097152;
            o = local >> 10; k = local & 1023;
        }
        float v = src[(long)o * in_ld + k];
        unsigned short hi = f2bf(v);
        dst[(long)o * 2 * K + k] = hi;
        dst[(long)o * 2 * K + K + k] = f2bf(v - bf2f(hi));
    } else if (bx < 6152) {
        for (int l = (bx - 6144) * 256 + tid; l < ZERO_WORDS; l += 2048) zbase[l] = 0.f;
    } else {
        int gid = (bx - 6152) * 4 + (tid >> 6);   // 0..1023
        int lane = tid & 63;
        int b = gid >> 9, o = gid & 511;
        float acc = 0.f;
        const float* wr = W1a + (long)o * 514;
        const float* zb = z + b * 512;
        for (int k = lane; k < 512; k += 64) acc += wr[k] * zb[k];
        #pragma unroll
        for (int off = 32; off > 0; off >>= 1) acc += __shfl_down(acc, off, 64);
        if (lane == 0) c1[gid] = acc + b1a[o];
    }
}

// ---------------- layer 1a: pointwise rank-2 update, emit packed [Xh|Xl] ----------------
__global__ void k_layer_a(const float* __restrict__ W1a, const float* __restrict__ c1,
                          unsigned short* __restrict__ X1) {
    int idx = blockIdx.x * 256 + threadIdx.x;   // 6144*512
    int o = idx & 511;
    int r = idx >> 9;
    int b, n, side;
    if (r < 2048) { b = r >> 10; n = r & 1023; side = 32; }
    else          { int r2 = r - 2048; b = r2 >> 11; n = r2 & 2047; side = 46; }
    int row = n / side, col = n % side;
    double inv = 1.0 / (double)(side - 1);
    float lx = (row == side - 1) ? 1.0f : (float)(row * inv);
    float ly = (col == side - 1) ? 1.0f : (float)(col * inv);
    float h = c1[b * 512 + o] + W1a[(long)o * 514 + 512] * lx + W1a[(long)o * 514 + 513] * ly;
    h = (h > 0.f) ? h : SLOPE * h;
    unsigned short hi = f2bf(h);
    X1[(long)r * 1024 + o] = hi;
    X1[(long)r * 1024 + 512 + o] = f2bf(h - bf2f(hi));
}

// ---------------- MFMA GEMM: TERMS=3 split-bf16, TERMS=1 plain bf16 ----------------
// Y[o][n] = leaky( W[o][:]·X[n][:] + bias ).  Optional epilogues:
//  - pack bf16 hi (+lo if lo_off) into Xn rows (n>=pack_min, row n-row_off, stride ldxn)
//  - head partial dots (Wx[3][512]) atomically accumulated into hacc[n][4]
//  - per-(b,o) max over n>=glob_min into globE (order-encoded u32)
template<int TERMS>
__global__ __launch_bounds__(256, 2) void k_gemm(
    const unsigned short* __restrict__ Wp, int ldw,
    const unsigned short* __restrict__ Xp, int ldx,
    int K,
    const float* __restrict__ bias, int bias_div,
    unsigned short* __restrict__ Xn, int ldxn, int lo_off, int row_off, int pack_min,
    const float* __restrict__ Wx, float* __restrict__ hacc,
    unsigned* __restrict__ globE, int glob_min) {

    __shared__ __align__(16) char sm[32768];
    const int t = threadIdx.x;
    const int nb0 = blockIdx.x * 64;
    const int ob0 = blockIdx.y * 64;

    const unsigned short* gp[8];
    int lo_[8];
    #pragma unroll
    for (int p = 0; p < 8; ++p) {
        const int T = p >> 1;
        if (TERMS == 1 && (T == 1 || T == 3)) continue;
        int j2 = ((p & 1) << 8) + t;
        int r = j2 >> 3, cl = j2 & 7, cs = cl ^ (r & 7);
        gp[p] = (T < 2)
            ? (Wp + (long)(ob0 + r) * ldw + ((T == 1) ? K : 0) + cs * 8)
            : (Xp + (long)(nb0 + r) * ldx + ((T == 3) ? K : 0) + cs * 8);
        lo_[p] = p * 4096 + t * 16;
    }

    const int lane = t & 63, w = t >> 6;
    const int wy = w >> 1, wx = w & 1;
    const int quad = lane >> 4, l15 = lane & 15;
    const int xm = l15 & 7;
    const int rowA = (wy * 32 + l15) * 128;
    const int rowB = (wx * 32 + l15) * 128;
    const int ca0 = (quad ^ xm) * 16;
    const int ca1 = ((quad + 4) ^ xm) * 16;

    f32x4 acc[2][2];
    #pragma unroll
    for (int i = 0; i < 2; ++i)
        #pragma unroll
        for (int j = 0; j < 2; ++j) { f32x4 zz = {0.f, 0.f, 0.f, 0.f}; acc[i][j] = zz; }

    for (int k0 = 0; k0 < K; k0 += 64) {
        #pragma unroll
        for (int p = 0; p < 8; ++p) {
            const int T = p >> 1;
            if (TERMS == 1 && (T == 1 || T == 3)) continue;
            __builtin_amdgcn_global_load_lds(
                (const __attribute__((address_space(1))) void*)(const void*)(gp[p] + k0),
                (__attribute__((address_space(3))) void*)(void*)(sm + lo_[p]),
                16, 0, 0);
        }
        __syncthreads();
        #pragma unroll
        for (int sub = 0; sub < 2; ++sub) {
            const int cb = (sub == 0) ? ca0 : ca1;
            bf16x8 ah[2], bh[2];
            #pragma unroll
            for (int i = 0; i < 2; ++i)
                ah[i] = *(const bf16x8*)(const void*)(sm + rowA + i * 2048 + cb);
            #pragma unroll
            for (int j = 0; j < 2; ++j)
                bh[j] = *(const bf16x8*)(const void*)(sm + 16384 + rowB + j * 2048 + cb);
            if (TERMS == 3) {
                bf16x8 al[2], bl[2];
                #pragma unroll
                for (int i = 0; i < 2; ++i)
                    al[i] = *(const bf16x8*)(const void*)(sm + 8192 + rowA + i * 2048 + cb);
                #pragma unroll
                for (int j = 0; j < 2; ++j)
                    bl[j] = *(const bf16x8*)(const void*)(sm + 24576 + rowB + j * 2048 + cb);
                #pragma unroll
                for (int i = 0; i < 2; ++i)
                    #pragma unroll
                    for (int j = 0; j < 2; ++j) {
                        acc[i][j] = __builtin_amdgcn_mfma_f32_16x16x32_bf16(ah[i], bh[j], acc[i][j], 0, 0, 0);
                        acc[i][j] = __builtin_amdgcn_mfma_f32_16x16x32_bf16(ah[i], bl[j], acc[i][j], 0, 0, 0);
                        acc[i][j] = __builtin_amdgcn_mfma_f32_16x16x32_bf16(al[i], bh[j], acc[i][j], 0, 0, 0);
                    }
            } else {
                #pragma unroll
                for (int i = 0; i < 2; ++i)
                    #pragma unroll
                    for (int j = 0; j < 2; ++j)
                        acc[i][j] = __builtin_amdgcn_mfma_f32_16x16x32_bf16(ah[i], bh[j], acc[i][j], 0, 0, 0);
            }
        }
        __syncthreads();
    }

    // ---- epilogue ----
    float val[2][2][4];
    #pragma unroll
    for (int j = 0; j < 2; ++j) {
        int n = nb0 + wx * 32 + j * 16 + l15;
        int bidx0 = (bias_div >= (1 << 29)) ? 0 : (n / bias_div) * 512;
        #pragma unroll
        for (int i = 0; i < 2; ++i) {
            int ob = ob0 + wy * 32 + i * 16 + quad * 4;
            #pragma unroll
            for (int r = 0; r < 4; ++r) {
                float x = acc[i][j][r] + bias[bidx0 + ob + r];
                val[i][j][r] = (x > 0.f) ? x : SLOPE * x;
            }
        }
        if (Xn && n >= pack_min) {
            long nl = n - row_off;
            #pragma unroll
            for (int i = 0; i < 2; ++i) {
                int ob = ob0 + wy * 32 + i * 16 + quad * 4;
                u16x4 h4;
                #pragma unroll
                for (int r = 0; r < 4; ++r) h4[r] = f2bf(val[i][j][r]);
                *(u16x4*)(void*)(Xn + nl * ldxn + ob) = h4;
                if (lo_off) {
                    u16x4 l4;
                    #pragma unroll
                    for (int r = 0; r < 4; ++r) l4[r] = f2bf(val[i][j][r] - bf2f(h4[r]));
                    *(u16x4*)(void*)(Xn + nl * ldxn + lo_off + ob) = l4;
                }
            }
        }
    }

    if (hacc) {
        __syncthreads();
        float* smh = (float*)sm;                     // [64][4]
        unsigned* smg = (unsigned*)(sm + 1024);      // [64]
        if (t < 256) smh[t] = 0.f;
        if (t < 64) smg[t] = 0u;
        __syncthreads();
        float wxv[3][2][4];
        #pragma unroll
        for (int ch = 0; ch < 3; ++ch)
            #pragma unroll
            for (int i = 0; i < 2; ++i)
                #pragma unroll
                for (int r = 0; r < 4; ++r)
                    wxv[ch][i][r] = Wx[ch * 512 + ob0 + wy * 32 + i * 16 + quad * 4 + r];
        #pragma unroll
        for (int j = 0; j < 2; ++j) {
            int nl = wx * 32 + j * 16 + l15;
            float p0 = 0.f, p1 = 0.f, p2 = 0.f;
            #pragma unroll
            for (int i = 0; i < 2; ++i)
                #pragma unroll
                for (int r = 0; r < 4; ++r) {
                    float v = val[i][j][r];
                    p0 += v * wxv[0][i][r];
                    p1 += v * wxv[1][i][r];
                    p2 += v * wxv[2][i][r];
                }
            atomicAdd(&smh[nl * 4 + 0], p0);
            atomicAdd(&smh[nl * 4 + 1], p1);
            atomicAdd(&smh[nl * 4 + 2], p2);
        }
        if (globE && nb0 >= glob_min) {
            #pragma unroll
            for (int i = 0; i < 2; ++i)
                #pragma unroll
                for (int r = 0; r < 4; ++r) {
                    float mx = fmaxf(val[i][0][r], val[i][1][r]);
                    atomicMax(&smg[wy * 32 + i * 16 + quad * 4 + r], fenc(mx));
                }
        }
        __syncthreads();
        if (t < 64) {
            atomicAdd(&hacc[(long)(nb0 + t) * 4 + 0], smh[t * 4 + 0]);
            atomicAdd(&hacc[(long)(nb0 + t) * 4 + 1], smh[t * 4 + 1]);
            atomicAdd(&hacc[(long)(nb0 + t) * 4 + 2], smh[t * 4 + 2]);
            if (globE && nb0 >= glob_min) {
                int b = (nb0 - glob_min) >> 11;
                atomicMax(&globE[b * 512 + ob0 + t], smg[t]);
            }
        }
    }
}

// ---------------- finalize stage-1: sigmoid heads + gbias GEMV ----------------
__global__ void k_finalize(const float* __restrict__ bx1, const float* __restrict__ hacc1,
                           float* __restrict__ out0, float* __restrict__ out2,
                           const float* __restrict__ W2a, const float* __restrict__ b2a,
                           const unsigned* __restrict__ globE, float* __restrict__ gbias) {
    int bx = blockIdx.x, tid = threadIdx.x;
    if (bx < 24) {
        int r = bx * 256 + tid;    // 0..6143
        float* dst = (r < 2048) ? (out0 + (long)r * 3) : (out2 + (long)(r - 2048) * 3);
        #pragma unroll
        for (int ch = 0; ch < 3; ++ch) {
            float a = hacc1[(long)r * 4 + ch] + bx1[ch];
            dst[ch] = 1.f / (1.f + expf(-a)) - 0.5f;
        }
    } else {
        int gid = (bx - 24) * 4 + (tid >> 6);   // 0..1023
        int lane = tid & 63;
        int b = gid >> 9, o = gid & 511;
        float acc = 0.f;
        const float* wr = W2a + (long)o * 1536 + 1024;
        for (int k = lane; k < 512; k += 64) acc += wr[k] * fdec(globE[b * 512 + k]);
        #pragma unroll
        for (int off = 32; off > 0; off >>= 1) acc += __shfl_down(acc, off, 64);
        if (lane == 0) gbias[gid] = acc + b2a[o];
    }
}

// ---------------- ball query (parallel compaction) + bf16 gather-max ----------------
// X2P rows: [4096][1024]: cols 0..511 = h3 hi (written by gemm1c), 512..1023 = local (here)
__global__ __launch_bounds__(256) void k_ball(const float* __restrict__ fine,
                                              unsigned short* __restrict__ X2P) {
    int i = blockIdx.x, b = blockIdx.y;
    int tid = threadIdx.x, lane = tid & 63, wv = tid >> 6;
    __shared__ int idxl[64];
    __shared__ int wcnt[4];
    __shared__ float part[8][256];
    const float* fb = fine + (long)b * N2 * 3;
    float xi = fb[i * 3 + 0], yi = fb[i * 3 + 1], zi = fb[i * 3 + 2];
    float sqi = __fadd_rn(__fadd_rn(__fmul_rn(xi, xi), __fmul_rn(yi, yi)), __fmul_rn(zi, zi));
    int cnt = 0;
    for (int it = 0; it < N2 / 256; ++it) {
        int j = it * 256 + tid;
        float xj = fb[j * 3 + 0], yj = fb[j * 3 + 1], zj = fb[j * 3 + 2];
        float sqj = __fadd_rn(__fadd_rn(__fmul_rn(xj, xj), __fmul_rn(yj, yj)), __fmul_rn(zj, zj));
        float dot = __fadd_rn(__fadd_rn(__fmul_rn(xi, xj), __fmul_rn(yi, yj)), __fmul_rn(zi, zj));
        float d2 = __fsub_rn(__fadd_rn(sqi, sqj), __fmul_rn(2.0f, dot));
        bool pred = d2 < 0.01f;
        unsigned long long m = __ballot(pred);
        if (lane == 0) wcnt[wv] = __popcll(m);
        __syncthreads();
        int wbase = cnt;
        #pragma unroll
        for (int q = 0; q < 3; ++q) { if (q < wv) wbase += wcnt[q]; }
        int total = wcnt[0] + wcnt[1] + wcnt[2] + wcnt[3];
        int rank = wbase + __popcll(m & ((1ull << lane) - 1ull));
        if (pred && rank < 64) idxl[rank] = j;
        cnt += total;
        if (cnt >= 64) break;       // uniform
        __syncthreads();
    }
    __syncthreads();
    int m = min(cnt, 64);

    const unsigned short* hb = X2P + (long)b * N2 * 1024;
    int g = tid & 63, q = tid >> 6;
    float mx[8];
    #pragma unroll
    for (int r = 0; r < 8; ++r) mx[r] = -1e30f;
    for (int jj = q; jj < m; jj += 4) {
        u16x8 v = *(const u16x8*)(const void*)(hb + (long)idxl[jj] * 1024 + g * 8);
        #pragma unroll
        for (int r = 0; r < 8; ++r) mx[r] = fmaxf(mx[r], bf2f(v[r]));
    }
    #pragma unroll
    for (int r = 0; r < 8; ++r) part[r][tid] = mx[r];
    __syncthreads();
    if (tid < 64) {
        unsigned short* orow = X2P + (long)(b * N2 + i) * 1024;
        u16x8 hi;
        #pragma unroll
        for (int r = 0; r < 8; ++r) {
            float v0 = fmaxf(fmaxf(part[r][tid], part[r][tid + 64]),
                             fmaxf(part[r][tid + 128], part[r][tid + 192]));
            hi[r] = (unsigned short)(__float_as_uint(v0) >> 16);   // exact: bf16-valued
        }
        *(u16x8*)(void*)(orow + 512 + tid * 8) = hi;
    }
}

// ---------------- finalize stage-2: out1 = fine + 0.1*(sigmoid-0.5) ----------------
__global__ void k_final2(const float* __restrict__ bx2, const float* __restrict__ hacc2,
                         const float* __restrict__ fine, float* __restrict__ out1) {
    int r = blockIdx.x * 256 + threadIdx.x;   // 0..4095
    #pragma unroll
    for (int ch = 0; ch < 3; ++ch) {
        float a = hacc2[(long)r * 4 + ch] + bx2[ch];
        out1[(long)r * 3 + ch] = fine[(long)r * 3 + ch] + 0.1f * (1.f / (1.f + expf(-a)) - 0.5f);
    }
}

// ---------------- launch ----------------
extern "C" void kernel_launch(void* const* d_in, const int* in_sizes, int n_in,
                              void* d_out, int out_size, void* d_ws, size_t ws_size,
                              hipStream_t stream) {
    const float* z   = (const float*)d_in[0];
    const float* W1a = (const float*)d_in[1];
    const float* b1a = (const float*)d_in[2];
    const float* W1b = (const float*)d_in[3];
    const float* b1b = (const float*)d_in[4];
    const float* W1c = (const float*)d_in[5];
    const float* b1c = (const float*)d_in[6];
    const float* Wx1 = (const float*)d_in[7];
    const float* bx1 = (const float*)d_in[8];
    const float* W2a = (const float*)d_in[9];
    const float* b2a = (const float*)d_in[10];
    const float* W2b = (const float*)d_in[11];
    const float* b2b = (const float*)d_in[12];
    const float* W2c = (const float*)d_in[13];
    const float* b2c = (const float*)d_in[14];
    const float* Wx2 = (const float*)d_in[15];
    const float* bx2 = (const float*)d_in[16];

    char* wsb = (char*)d_ws;
    unsigned short* WP   = (unsigned short*)(wsb + OFF_WP);
    unsigned short* X1P  = (unsigned short*)(wsb + OFF_X1P);   // [6144][1024] hi|lo
    unsigned short* XMP  = (unsigned short*)(wsb + OFF_XMP);   // [6144][1024] hi|lo
    unsigned short* X2P  = (unsigned short*)(wsb + OFF_X2P);   // [4096][1024] h3|local (hi)
    unsigned short* X3P  = (unsigned short*)(wsb + OFF_X3P);   // [4096][512] hi
    unsigned short* X4P  = (unsigned short*)(wsb + OFF_X4P);   // [4096][512] hi
    float*    c1    = (float*)(wsb + OFF_C1);
    unsigned* globE = (unsigned*)(wsb + OFF_GLOBE);
    float*    gbias = (float*)(wsb + OFF_GBIAS);
    float*    hacc1 = (float*)(wsb + OFF_HACC1);
    float*    hacc2 = (float*)(wsb + OFF_HACC2);

    unsigned short* WP1b = WP;
    unsigned short* WP1c = WP + 524288;
    unsigned short* WP2b = WP + 1048576;
    unsigned short* WP2c = WP + 1572864;
    unsigned short* WP2a = WP + 2097152;

    float* out0 = (float*)d_out;          // (2,1024,3)
    float* out1 = out0 + B * N1 * 3;      // (2,2048,3)
    float* out2 = out1 + B * N2 * 3;      // (2,2048,3) fine_points
    float* fine = out2;

    const int BIG = 1 << 30;

    k_prep<<<6408, 256, 0, stream>>>(W1b, W1c, W2b, W2c, W2a, WP, z, W1a, b1a, c1,
                                     (float*)(wsb + OFF_GLOBE));
    k_layer_a<<<12288, 256, 0, stream>>>(W1a, c1, X1P);

    // stage-1 MLP (split-bf16, N1+N2 fused: 6144 rows)
    k_gemm<3><<<dim3(96, 8), 256, 0, stream>>>(WP1b, 1024, X1P, 1024, 512, b1b, BIG,
                                               XMP, 1024, 512, 0, 0,
                                               nullptr, nullptr, nullptr, 0);
    k_gemm<3><<<dim3(96, 8), 256, 0, stream>>>(WP1c, 1024, XMP, 1024, 512, b1c, BIG,
                                               X2P, 1024, 0, 2048, 2048,
                                               Wx1, hacc1, globE, 2048);
    k_finalize<<<280, 256, 0, stream>>>(bx1, hacc1, out0, out2, W2a, b2a, globE, gbias);
    k_ball<<<dim3(N2, B), 256, 0, stream>>>(fine, X2P);

    // stage-2 MLP (plain bf16, 4096 rows)
    k_gemm<1><<<dim3(64, 8), 256, 0, stream>>>(WP2a, 2048, X2P, 1024, 1024, gbias, 2048,
                                               X3P, 512, 0, 0, 0,
                                               nullptr, nullptr, nullptr, 0);
    k_gemm<1><<<dim3(64, 8), 256, 0, stream>>>(WP2b, 1024, X3P, 512, 512, b2b, BIG,
                                               X4P, 512, 0, 0, 0,
                                               nullptr, nullptr, nullptr, 0);
    k_gemm<1><<<dim3(64, 8), 256, 0, stream>>>(WP2c, 1024, X4P, 512, 512, b2c, BIG,
                                               nullptr, 0, 0, 0, 0,
                                               Wx2, hacc2, nullptr, 0);
    k_final2<<<16, 256, 0, stream>>>(bx2, hacc2, fine, out1);
}